// Round 7
// baseline (119.541 us; speedup 1.0000x reference)
//
#include <hip/hip_runtime.h>

#define N 8000
#define SEQ 200
#define MAX_STEPS 199

#define REG_BLOCKS 2000
#define REG_THREADS 256
#define NN4 16000000                   // N*N/4 float4 per matrix
#define CHUNK 8000                     // f4 per matrix per block (2000*8000 = NN4)
#define FULL_K 31                      // 31*256 = 7936; tail covers 64 (t < 64)

typedef float f4 __attribute__((ext_vector_type(4)));

__device__ __forceinline__ float log_sum4(f4 v) {
    // log(|x|+1) = ln2 * log2(|x|+1); ln2*0.5 folded into the final atomic.
    return __log2f(fabsf(v[0]) + 1.0f) + __log2f(fabsf(v[1]) + 1.0f) +
           __log2f(fabsf(v[2]) + 1.0f) + __log2f(fabsf(v[3]) + 1.0f);
}

// -------------------------------------------------------------------------
// K1: zero out; gather D[t][i] = s_t*pe[a_t][a_i] + (1-s_t)*ne[a_t][a_i]
//     into workspace. 39601 threads over 155 blocks -> scatter is parallel.
// -------------------------------------------------------------------------
__global__ void k_init_gather(const int* __restrict__ a,
                              const float* __restrict__ s,
                              const float* __restrict__ pe,
                              const float* __restrict__ ne,
                              float* __restrict__ D, int useD,
                              float* __restrict__ out) {
    if (blockIdx.x == 0 && threadIdx.x == 0) out[0] = 0.0f;
    if (!useD) return;

    __shared__ int   sa[MAX_STEPS];
    __shared__ float ss[MAX_STEPS];
    for (int i = threadIdx.x; i < MAX_STEPS; i += blockDim.x) {
        sa[i] = a[i];
        ss[i] = s[i];
    }
    __syncthreads();

    int idx = blockIdx.x * blockDim.x + threadIdx.x;
    const int total = MAX_STEPS * MAX_STEPS;
    if (idx < total) {
        int t = idx / MAX_STEPS;
        int i = idx - t * MAX_STEPS;
        float st = ss[t];
        size_t off = (size_t)sa[t] * N + (size_t)sa[i];
        float d = st * pe[off] + (1.0f - st) * ne[off];
        D[idx] = d;
    }
}

// -------------------------------------------------------------------------
// K2: regularizer. NT loads (R6, kept). NEW: per-block CONTIGUOUS chunks —
//     block b owns f4[b*8000 .. b*8000+8000) of each matrix, swept in
//     sequential 4 KB steps -> sequential per-block DRAM streams.
// -------------------------------------------------------------------------
__global__ void __launch_bounds__(REG_THREADS)
k_reg(const float* __restrict__ pe,
      const float* __restrict__ ne,
      float* __restrict__ out) {
    const f4* __restrict__ pe4 = (const f4*)pe;
    const f4* __restrict__ ne4 = (const f4*)ne;
    const size_t base = (size_t)blockIdx.x * CHUNK + threadIdx.x;

    float acc = 0.0f;
    #pragma unroll 2
    for (int k = 0; k < FULL_K; ++k) {
        size_t p = base + (size_t)k * REG_THREADS;
        f4 v = __builtin_nontemporal_load(&pe4[p]);
        f4 w = __builtin_nontemporal_load(&ne4[p]);
        acc += log_sum4(v);
        acc += log_sum4(w);
    }
    // tail: 64 f4 per chunk (threads 0..63)
    if (threadIdx.x < CHUNK - FULL_K * REG_THREADS) {
        size_t p = base + (size_t)FULL_K * REG_THREADS;
        f4 v = __builtin_nontemporal_load(&pe4[p]);
        f4 w = __builtin_nontemporal_load(&ne4[p]);
        acc += log_sum4(v);
        acc += log_sum4(w);
    }

    // wave64 reduce
    #pragma unroll
    for (int o = 32; o > 0; o >>= 1) acc += __shfl_down(acc, o);
    __shared__ float wsum[REG_THREADS / 64];
    int lane = threadIdx.x & 63;
    int wid  = threadIdx.x >> 6;
    if (lane == 0) wsum[wid] = acc;
    __syncthreads();
    if (threadIdx.x == 0) {
        float b = 0.0f;
        #pragma unroll
        for (int w = 0; w < REG_THREADS / 64; ++w) b += wsum[w];
        // 0.5 * ln(2) folded here (log2 -> ln conversion)
        atomicAdd(out, 0.34657359027997264f * b);
    }
}

// -------------------------------------------------------------------------
// K3: sequential loss from D (coalesced columns, cache-resident). 1 block.
// -------------------------------------------------------------------------
__global__ void k_loss(const int* __restrict__ a,
                       const float* __restrict__ s,
                       const float* __restrict__ pe,
                       const float* __restrict__ ne,
                       const float* __restrict__ kp,
                       const float* __restrict__ D, int useD,
                       float* __restrict__ out) {
    __shared__ int   sa[MAX_STEPS];
    __shared__ float ss[MAX_STEPS];
    int tid = threadIdx.x;
    for (int i = tid; i < MAX_STEPS; i += blockDim.x) {
        sa[i] = a[i];
        ss[i] = s[i];
    }
    __syncthreads();

    __shared__ int V;
    if (tid == 0) {
        int v = MAX_STEPS;
        for (int t = 0; t < MAX_STEPS; ++t) {
            if (ss[t] < 0.0f) { v = t; break; }
        }
        V = v;
    }
    __syncthreads();

    float li = 0.0f;
    if (tid < MAX_STEPS && tid < V) {
        int j = sa[tid];
        float k = kp[j];
        if (useD) {
            int t = 0;
            for (; t + 8 <= tid; t += 8) {
                float d[8];
                #pragma unroll
                for (int u = 0; u < 8; ++u) d[u] = D[(t + u) * MAX_STEPS + tid];
                #pragma unroll
                for (int u = 0; u < 8; ++u)
                    k = fminf(fmaxf(k + d[u], -30.0f), 30.0f);
            }
            for (; t < tid; ++t) {
                float d = D[t * MAX_STEPS + tid];
                k = fminf(fmaxf(k + d, -30.0f), 30.0f);
            }
        } else {
            for (int t = 0; t < tid; ++t) {
                float st = ss[t];
                size_t off = (size_t)sa[t] * N + (size_t)j;
                float d = st * pe[off] + (1.0f - st) * ne[off];
                k = fminf(fmaxf(k + d, -30.0f), 30.0f);
            }
        }
        float p = fminf(fmaxf(k, 0.01f), 0.99f);
        li = -(ss[tid] * logf(p) + (1.0f - ss[tid]) * logf(1.0f - p));
    }

    #pragma unroll
    for (int o = 32; o > 0; o >>= 1) li += __shfl_down(li, o);
    __shared__ float wsum[4];
    int lane = tid & 63;
    int wid  = tid >> 6;
    if (lane == 0) wsum[wid] = li;
    __syncthreads();
    if (tid == 0) {
        float total = wsum[0] + wsum[1] + wsum[2] + wsum[3];
        atomicAdd(out, total);
    }
}

extern "C" void kernel_launch(void* const* d_in, const int* in_sizes, int n_in,
                              void* d_out, int out_size, void* d_ws, size_t ws_size,
                              hipStream_t stream) {
    const int*   a  = (const int*)d_in[0];
    const float* s  = (const float*)d_in[1];
    const float* pe = (const float*)d_in[2];
    const float* ne = (const float*)d_in[3];
    const float* kp = (const float*)d_in[4];
    float* out = (float*)d_out;

    float* D = (float*)d_ws;
    int useD = (ws_size >= sizeof(float) * MAX_STEPS * MAX_STEPS) ? 1 : 0;

    const int gatherBlocks = (MAX_STEPS * MAX_STEPS + 255) / 256;
    k_init_gather<<<gatherBlocks, 256, 0, stream>>>(a, s, pe, ne, D, useD, out);
    k_reg<<<REG_BLOCKS, REG_THREADS, 0, stream>>>(pe, ne, out);
    k_loss<<<1, 256, 0, stream>>>(a, s, pe, ne, kp, D, useD, out);
}